// Round 4
// baseline (324.005 us; speedup 1.0000x reference)
//
#include <hip/hip_runtime.h>
#include <math.h>

// Problem constants
#define BB 16
#define NN 1024
#define DD 512
#define KK 8
#define EPS_ 1e-8f
#define LN_EPS_ 1e-5f
// -0.5 * D * log(2*pi)
#define GLL_C0 (-470.4965290007924f)

typedef __attribute__((ext_vector_type(8))) short short8;
typedef __attribute__((ext_vector_type(4))) short short4v;
typedef __attribute__((ext_vector_type(4))) float f32x4;
typedef __attribute__((ext_vector_type(4))) int int4v;

static __device__ inline short f2bf(float f) {
    unsigned u = __builtin_bit_cast(unsigned, f);
    u = (u + 0x7fff + ((u >> 16) & 1)) >> 16;
    return (short)u;
}
static __device__ inline float bf2f(short s) {
    unsigned u = ((unsigned)(unsigned short)s) << 16;
    return __builtin_bit_cast(float, u);
}

struct Params {
    const float *emb, *noise_init, *noise_final, *slots_mu, *slots_logsg,
                *mixing_co, *Wk, *bk, *Wq, *bq, *Wv, *bv, *ln_g, *ln_b;
    float *out;
    // workspace
    float *queries, *attn;   // attn slot kept for layout, unused
    float *s1c, *s2c;        // [3][BB*KK*DD] compact moment accumulators
    float *colsum;           // [3][BB*KK]  (slots are cache-line disjoint: 512B each)
    int   *cnt;              // [BB] monotone per-batch sync counters
    short *Abf, *Kbf, *Vbf, *WtKV, *WqT, *slotbf;
};

// ===========================================================================
// 1) pre: u in [0,4992) : LN+cast | weight transpose | slot init
//    (verified correct, unchanged)
// ===========================================================================
__global__ __launch_bounds__(256) void k_pre(Params p)
{
    __shared__ __align__(16) short eb[4352];
    int u = blockIdx.x, tid = threadIdx.x;
    if (u < 4096) {
        int row  = u * 4 + (tid >> 6);
        int lane = tid & 63;
        const float* e = p.emb + (size_t)row * DD + lane * 8;
        float4 v0 = *(const float4*)e;
        float4 v1 = *(const float4*)(e + 4);
        float v[8] = {v0.x, v0.y, v0.z, v0.w, v1.x, v1.y, v1.z, v1.w};
        float s = 0.0f;
#pragma unroll
        for (int j = 0; j < 8; j++) s += v[j];
#pragma unroll
        for (int off = 32; off; off >>= 1) s += __shfl_xor(s, off);
        float m = s * (1.0f / DD);
        float vs = 0.0f;
#pragma unroll
        for (int j = 0; j < 8; j++) { float d = v[j] - m; vs = fmaf(d, d, vs); }
#pragma unroll
        for (int off = 32; off; off >>= 1) vs += __shfl_xor(vs, off);
        float rstd = rsqrtf(vs * (1.0f / DD) + LN_EPS_);

        float4 g0 = *(const float4*)&p.ln_g[lane * 8];
        float4 g1 = *(const float4*)&p.ln_g[lane * 8 + 4];
        float4 b0 = *(const float4*)&p.ln_b[lane * 8];
        float4 b1 = *(const float4*)&p.ln_b[lane * 8 + 4];
        float g[8] = {g0.x, g0.y, g0.z, g0.w, g1.x, g1.y, g1.z, g1.w};
        float bb[8] = {b0.x, b0.y, b0.z, b0.w, b1.x, b1.y, b1.z, b1.w};
        short8 o;
#pragma unroll
        for (int j = 0; j < 8; j++) o[j] = f2bf(fmaf((v[j] - m) * rstd, g[j], bb[j]));
        *(short8*)&p.Abf[(size_t)row * DD + lane * 8] = o;
    } else if (u < 4864) {
        int idx = u - 4096;
        int z = idx >> 8, rem = idx & 255;
        const float* W = (z == 0) ? p.Wk : (z == 1) ? p.Wv : p.Wq;
        short* T; int nbase;
        if (z < 2) { T = p.WtKV; nbase = z * 512; } else { T = p.WqT; nbase = 0; }
        int k0 = (rem & 15) * 32, n0 = (rem >> 4) * 32;
        int tx = tid & 31, ty = tid >> 5;
        float (*t)[33] = (float (*)[33])eb;
#pragma unroll
        for (int q = 0; q < 4; q++)
            t[ty + q * 8][tx] = W[(size_t)(k0 + ty + q * 8) * DD + n0 + tx];
        __syncthreads();
#pragma unroll
        for (int q = 0; q < 4; q++)
            T[(size_t)(nbase + n0 + ty + q * 8) * DD + k0 + tx] = f2bf(t[tx][ty + q * 8]);
    } else {
        int idx = u - 4864;
        int b = idx >> 3, k = idx & 7;
#pragma unroll
        for (int q = 0; q < 2; q++) {
            int d = tid + q * 256;
            float sg = expf(p.slots_logsg[k * DD + d]);
            float sl = fmaf(sg, p.noise_init[((size_t)(b * KK + k)) * DD + d],
                            p.slots_mu[k * DD + d]);
            p.slotbf[((size_t)(b * KK + k)) * DD + d] = f2bf(sl);
        }
    }
}

// ===========================================================================
// 2) gemm: u in [0,1032) : 128x128 MFMA GEMM, global_load_lds staging
//    (round-2 version, verified).  Spare qmode blocks (u in [1028,1032))
//    zero ALL moment/colsum/cnt buffers (flushed to coherent point at this
//    kernel's end-of-kernel release -> safe for k_iter's atomics).
// ===========================================================================
__global__ __launch_bounds__(256) void k_gemm(Params p)
{
    __shared__ __align__(16) short smem[32768];   // 64 KB: As0|As1|Bs0|Bs1
    int u = blockIdx.x, tid = threadIdx.x;
    int w = tid >> 6, l = tid & 63;
    int x, by, qmode;
    if (u >= 1024) {
        qmode = 1; x = u - 1024;
        if (x >= 4) {
            int gidx = (x - 4) * 256 + tid;          // 0..1023
            for (int i = gidx; i < 3 * BB * KK * DD; i += 1024) {
                p.s1c[i] = 0.0f;
                p.s2c[i] = 0.0f;
            }
            if (gidx < 3 * BB * KK) p.colsum[gidx] = 0.0f;
            if (gidx < BB) p.cnt[gidx] = 0;
            return;
        }
        by = 128;
    } else { qmode = 0; x = u >> 7; by = u & 127; }
    const short* A  = qmode ? p.slotbf : p.Abf + (size_t)by * 128 * DD;
    const short* Bt = qmode ? p.WqT : p.WtKV;
    int row0 = qmode ? 0 : by * 128;
    int col0 = x * 128;

    int sr = l >> 3;
    int sg_off = ((l & 7) ^ sr) * 8;
    int mq = (w & 1) * 64, nq = (w >> 1) * 64;
    int fr = l & 15;
    int orow = (l >> 4) * 4, ocol = l & 15;

    auto STAGE = [&](int k0, int buf) {
        short* As_ = smem + buf * 8192;
        short* Bs_ = smem + 16384 + buf * 8192;
#pragma unroll
        for (int j = 0; j < 4; j++) {
            int rbj = w * 32 + j * 8;
            int r   = rbj + sr;
            __builtin_amdgcn_global_load_lds(
                (const __attribute__((address_space(1))) unsigned int*)
                    (A + (size_t)r * DD + k0 + sg_off),
                (__attribute__((address_space(3))) unsigned int*)
                    &As_[rbj * 64 + l * 8], 16, 0, 0);
            __builtin_amdgcn_global_load_lds(
                (const __attribute__((address_space(1))) unsigned int*)
                    (Bt + (size_t)(col0 + r) * DD + k0 + sg_off),
                (__attribute__((address_space(3))) unsigned int*)
                    &Bs_[rbj * 64 + l * 8], 16, 0, 0);
        }
    };

    f32x4 acc[4][4] = {};
    STAGE(0, 0);
    __syncthreads();
    for (int i = 0; i < 8; i++) {
        if (i < 7) STAGE((i + 1) * 64, (i + 1) & 1);   // in flight during compute
        const short* As_ = smem + (i & 1) * 8192;
        const short* Bs_ = smem + 16384 + (i & 1) * 8192;
#pragma unroll
        for (int kk = 0; kk < 2; kk++) {
            int g = kk * 4 + (l >> 4);
            short8 af[4], bfv[4];
#pragma unroll
            for (int mi = 0; mi < 4; mi++)
                af[mi] = *(const short8*)&As_[(mq + mi * 16 + fr) * 64 + (g ^ (fr & 7)) * 8];
#pragma unroll
            for (int ni = 0; ni < 4; ni++)
                bfv[ni] = *(const short8*)&Bs_[(nq + ni * 16 + fr) * 64 + (g ^ (fr & 7)) * 8];
#pragma unroll
            for (int mi = 0; mi < 4; mi++)
#pragma unroll
                for (int ni = 0; ni < 4; ni++)
                    acc[mi][ni] = __builtin_amdgcn_mfma_f32_16x16x32_bf16(
                        af[mi], bfv[ni], acc[mi][ni], 0, 0, 0);
        }
        __syncthreads();                  // ONE barrier per iteration (drains vmcnt)
    }

    float bvv[4];
#pragma unroll
    for (int ni = 0; ni < 4; ni++) {
        int col = col0 + nq + ni * 16 + ocol;
        bvv[ni] = qmode ? p.bq[col] : (x < 4 ? p.bk[col] : p.bv[col - 512]);
    }

    if (qmode) {
#pragma unroll
        for (int ni = 0; ni < 4; ni++) {
            int col = col0 + nq + ni * 16 + ocol;
#pragma unroll
            for (int mi = 0; mi < 4; mi++)
#pragma unroll
                for (int r = 0; r < 4; r++)
                    p.queries[(size_t)(mq + mi * 16 + orow + r) * DD + col] =
                        acc[mi][ni][r] + bvv[ni];
        }
    } else {
        short* eb = smem;   // epilogue buffer (first 32 KB)
        short* dst = (x < 4) ? p.Kbf : p.Vbf;
        int ccol0 = (x & 3) * 128;
#pragma unroll
        for (int mi = 0; mi < 4; mi++)
#pragma unroll
            for (int r = 0; r < 4; r++) {
                int row = mq + mi * 16 + orow + r;
                int sw = ((row >> 2) & 3) << 1;
#pragma unroll
                for (int ni = 0; ni < 4; ni++) {
                    int colg = nq + ni * 16 + ocol;
                    eb[row * 128 + (((colg >> 3) ^ sw) * 8) + (colg & 7)] =
                        f2bf(acc[mi][ni][r] + bvv[ni]);
                }
            }
        __syncthreads();
#pragma unroll
        for (int i = 0; i < 8; i++) {
            int row = i * 16 + w * 4 + (l >> 4);
            int c = l & 15;
            int cc = c ^ (((row >> 2) & 3) << 1);
            short8 vv = *(const short8*)&eb[row * 128 + cc * 8];
            *(short8*)&dst[(size_t)(row0 + row) * 512 + ccol0 + c * 8] = vv;
        }
    }
}

// ===========================================================================
// 3) k_iter: ENTIRE iteration pipeline in one launch.  Grid 128 = 16 batches
//    x 8 chunks of 128 rows; 512 threads.  All co-resident (128 <= 256 CUs).
//    Per iteration:
//      phase F : recompute F (bf16) for batch b in LDS + off/mix
//                (it==0 from logsigma; it>0 from mom[it-1]/colsum[it-1],
//                 guarded by the per-batch spin of the previous iter).
//      phase A : verified MFMA gll over 4 sub-tiles of 32 rows; normalize;
//                asml in LDS; ONE colsum atomicAdd per col per wave.
//      phase B : verified 1-d/thread moment accumulation over 128 rows;
//                16 atomicAdds -> mom[it] (8-way contention, ~1M/iter).
//      sync    : threadfence + per-batch monotone counter; tid0 spins for
//                8*(it+1) with agent-scope acquire; all-thread fence after.
//    Epilogue: slots out (block's own batch slice) + attn^T straight from
//    block-local asml / colsum[2].  Replaces 6 kernels + attn round-trip.
// ===========================================================================
__global__ __launch_bounds__(512) void k_iter(Params p)
{
    __shared__ __align__(16) short F0L[16][520];   // 16.25 KB
    __shared__ __align__(16) short F1L[16][520];   // 16.25 KB
    __shared__ f32x4 red[3][2][64];                // 6 KB
    __shared__ __align__(16) float asml[128 * KK]; // 4 KB
    __shared__ float off_l[16], mix_l[16];

    int u = blockIdx.x, tid = threadIdx.x;
    int w = tid >> 6, l = tid & 63;
    int b = u >> 3, chunk = u & 7;
    int n0 = chunk * 128;
    int t = w & 1, ks = w >> 1;       // row-tile, K-split (0..3)

    for (int it = 0; it < 3; it++) {
        // ---- phase F: build F rows for batch b in LDS; off/mix ----
        {
            int k = w;                 // 8 waves -> slots 0..7
            const float* qrow = p.queries + ((size_t)(b * KK + k)) * DD;
            float inv = 0.0f, ssum = 0.0f;
            if (it > 0) {
                float cs = p.colsum[(it - 1) * (BB * KK) + b * KK + k];
                inv  = 1.0f / (cs + EPS_);
                ssum = cs * inv;
            }
            float c = 0.0f, ld = 0.0f;
            short8 f0v, f1v;
#pragma unroll
            for (int j = 0; j < 8; j++) {
                int d = l * 8 + j;
                float sg;
                if (it == 0) {
                    sg = expf(p.slots_logsg[k * DD + d]);
                } else {
                    float s1 = p.s1c[(it - 1) * (BB * KK * DD) + (b * KK + k) * DD + d];
                    float s2 = p.s2c[(it - 1) * (BB * KK * DD) + (b * KK + k) * DD + d];
                    float m  = s1 * inv;
                    sg = s2 * inv - m * m * (2.0f - ssum);
                }
                float iv = 1.0f / (sg * sg + EPS_);
                float qv = qrow[d];
                f0v[j] = f2bf(-0.5f * iv);
                f1v[j] = f2bf(qv * iv);
                c  = fmaf(qv * qv, iv, c);
                ld += logf(fabsf(sg) + EPS_);
            }
            *(short8*)&F0L[k][l * 8] = f0v;
            *(short8*)&F1L[k][l * 8] = f1v;
            if (it == 0) {
                short8 zz = {};
                *(short8*)&F0L[k + 8][l * 8] = zz;     // zero-pad slots 8..15
                *(short8*)&F1L[k + 8][l * 8] = zz;
            }
#pragma unroll
            for (int m_ = 32; m_; m_ >>= 1) { c += __shfl_xor(c, m_); ld += __shfl_xor(ld, m_); }
            if (l == 0) {
                off_l[k] = GLL_C0 - 0.5f * ld - 0.5f * c;
                mix_l[k] = (it == 0) ? p.mixing_co[k] : ssum * (1.0f / NN);
                if (it == 0) { off_l[k + 8] = 0.0f; mix_l[k + 8] = 0.0f; }
            }
        }
        __syncthreads();

        // ---- phase A: 4 sub-tiles of 32 rows (verified math) ----
        float csl = 0.0f;
#pragma unroll
        for (int st = 0; st < 4; st++) {
            const short* Ka = p.Kbf
                + ((size_t)(b * NN + n0 + st * 32 + t * 16 + (l & 15))) * 512
                + ks * 128 + (l >> 4) * 8;
            const short* F0r = &F0L[l & 15][ks * 128 + (l >> 4) * 8];
            const short* F1r = &F1L[l & 15][ks * 128 + (l >> 4) * 8];
            f32x4 acc0 = {}, acc1 = {};
#pragma unroll
            for (int j = 0; j < 4; j++) {
                short8 kf = *(const short8*)&Ka[j * 32];
                short8 f0 = *(const short8*)&F0r[j * 32];        // -0.5*invvar
                short8 f1 = *(const short8*)&F1r[j * 32];        // q*invvar
                short8 k2;
#pragma unroll
                for (int e = 0; e < 8; e++) {
                    float kv = bf2f(kf[e]);
                    k2[e] = f2bf(kv * kv);
                }
                acc0 = __builtin_amdgcn_mfma_f32_16x16x32_bf16(k2, f0, acc0, 0, 0, 0);
                acc1 = __builtin_amdgcn_mfma_f32_16x16x32_bf16(kf, f1, acc1, 0, 0, 0);
            }
            f32x4 acc = acc0 + acc1;
            if (ks) red[ks - 1][t][l] = acc;
            __syncthreads();
            if (ks == 0) {
#pragma unroll
                for (int i = 0; i < 3; i++) acc += red[i][t][l];
                int col = l & 15;
                int rloc = st * 32 + t * 16 + (l >> 4) * 4;
                float offv = off_l[col];
                float mixv = mix_l[col];
                float a[4], den[4];
#pragma unroll
                for (int r = 0; r < 4; r++) { a[r] = mixv * (acc[r] + offv); den[r] = a[r]; }
#pragma unroll
                for (int mask = 1; mask <= 8; mask <<= 1)
#pragma unroll
                    for (int r = 0; r < 4; r++) den[r] += __shfl_xor(den[r], mask);
                if (col < KK) {
#pragma unroll
                    for (int r = 0; r < 4; r++) {
                        float vv = a[r] / den[r];
                        asml[(rloc + r) * KK + col] = vv;
                        csl += vv;
                    }
                }
            }
            __syncthreads();
        }
        if (ks == 0) {
            csl += __shfl_xor(csl, 16);
            csl += __shfl_xor(csl, 32);
            if (l < KK) atomicAdd(&p.colsum[it * (BB * KK) + b * KK + l], csl);
        }

        // ---- phase B: 1 d-column/thread over 128 rows; atomics to mom[it] ----
        float s1[KK] = {}, s2[KK] = {};
        const short* vb = p.Vbf + ((size_t)(b * NN + n0)) * DD + tid;
#pragma unroll 4
        for (int nn = 0; nn < 128; nn++) {
            float v = bf2f(vb[(size_t)nn * DD]);
            float vq = v * v;
            float4 a0 = *(const float4*)&asml[nn * KK];
            float4 a1 = *(const float4*)&asml[nn * KK + 4];
            float aa[8] = {a0.x, a0.y, a0.z, a0.w, a1.x, a1.y, a1.z, a1.w};
#pragma unroll
            for (int k = 0; k < KK; k++) {
                s1[k] = fmaf(aa[k], v, s1[k]);
                s2[k] = fmaf(aa[k], vq, s2[k]);
            }
        }
        {
            float* s1d = p.s1c + it * (BB * KK * DD) + (size_t)b * KK * DD + tid;
            float* s2d = p.s2c + it * (BB * KK * DD) + (size_t)b * KK * DD + tid;
#pragma unroll
            for (int k = 0; k < KK; k++) {
                atomicAdd(&s1d[(size_t)k * DD], s1[k]);
                atomicAdd(&s2d[(size_t)k * DD], s2[k]);
            }
        }

        // ---- per-batch sync: monotone counter, agent-scope ----
        __threadfence();
        __syncthreads();
        if (tid == 0) {
            atomicAdd(&p.cnt[b], 1);
            int target = 8 * (it + 1);
            while (__hip_atomic_load(&p.cnt[b], __ATOMIC_ACQUIRE,
                                     __HIP_MEMORY_SCOPE_AGENT) < target)
                __builtin_amdgcn_s_sleep(1);
        }
        __syncthreads();
        __threadfence();
    }

    // ---- epilogue: slots output (block's own batch slice, gid>>12 == b) ----
    {
        int gid = u * 512 + tid;          // [0, 65536)
        int k = (gid >> 9) & 7;
        int bb_ = gid >> 12;
        float s1 = p.s1c[2 * (BB * KK * DD) + gid];
        float s2 = p.s2c[2 * (BB * KK * DD) + gid];
        float cs   = p.colsum[2 * (BB * KK) + bb_ * KK + k];
        float inv  = 1.0f / (cs + EPS_);
        float ssum = cs * inv;
        float m    = s1 * inv;
        float sg   = s2 * inv - m * m * (2.0f - ssum);
        p.out[gid] = fmaf(fmaxf(fabsf(sg), EPS_), p.noise_final[gid], m);
    }
    // ---- epilogue: attn^T straight from block-local asml ----
#pragma unroll
    for (int q = 0; q < 2; q++) {
        int idx = q * 512 + tid;          // [0, 1024)
        int k  = idx >> 7;
        int nn = idx & 127;
        float cs = p.colsum[2 * (BB * KK) + b * KK + k];
        p.out[(size_t)BB * KK * DD + (size_t)b * KK * NN + (size_t)k * NN + n0 + nn] =
            asml[nn * KK + k] / (cs + EPS_);
    }
}

// ===========================================================================
extern "C" void kernel_launch(void* const* d_in, const int* in_sizes, int n_in,
                              void* d_out, int out_size, void* d_ws, size_t ws_size,
                              hipStream_t stream)
{
    Params pp;
    pp.emb         = (const float*)d_in[0];
    pp.noise_init  = (const float*)d_in[1];
    pp.noise_final = (const float*)d_in[2];
    pp.slots_mu    = (const float*)d_in[3];
    pp.slots_logsg = (const float*)d_in[4];
    pp.mixing_co   = (const float*)d_in[5];
    pp.Wk          = (const float*)d_in[6];
    pp.bk          = (const float*)d_in[7];
    pp.Wq          = (const float*)d_in[8];
    pp.bq          = (const float*)d_in[9];
    pp.Wv          = (const float*)d_in[10];
    pp.bv          = (const float*)d_in[11];
    pp.ln_g        = (const float*)d_in[12];
    pp.ln_b        = (const float*)d_in[13];
    pp.out         = (float*)d_out;

    float* ws = (float*)d_ws;
    pp.queries = ws;                                  // 65536 f
    pp.attn    = pp.queries + BB * KK * DD;           // 131072 f (unused)
    pp.s1c     = pp.attn + BB * NN * KK;              // 3*65536 f
    pp.s2c     = pp.s1c + 3 * BB * KK * DD;           // 3*65536 f
    pp.colsum  = pp.s2c + 3 * BB * KK * DD;           // 3*128 f (512B slots)
    pp.cnt     = (int*)(pp.colsum + 3 * BB * KK);     // 16 ints
    pp.Abf     = (short*)(pp.cnt + 16);
    pp.Kbf     = pp.Abf + (size_t)BB * NN * DD;
    pp.Vbf     = pp.Kbf + (size_t)BB * NN * DD;
    pp.WtKV    = pp.Vbf + (size_t)BB * NN * DD;
    pp.WqT     = pp.WtKV + (size_t)1024 * DD;
    pp.slotbf  = pp.WqT + (size_t)DD * DD;

    k_pre<<<4992, 256, 0, stream>>>(pp);
    k_gemm<<<1032, 256, 0, stream>>>(pp);
    k_iter<<<128, 512, 0, stream>>>(pp);
}

// Round 5
// 222.522 us; speedup vs baseline: 1.4561x; 1.4561x over previous
//
#include <hip/hip_runtime.h>
#include <math.h>

// Problem constants
#define BB 16
#define NN 1024
#define DD 512
#define KK 8
#define EPS_ 1e-8f
#define LN_EPS_ 1e-5f
// -0.5 * D * log(2*pi)
#define GLL_C0 (-470.4965290007924f)

typedef __attribute__((ext_vector_type(8))) short short8;
typedef __attribute__((ext_vector_type(4))) short short4v;
typedef __attribute__((ext_vector_type(4))) float f32x4;
typedef __attribute__((ext_vector_type(4))) int int4v;

static __device__ inline short f2bf(float f) {
    unsigned u = __builtin_bit_cast(unsigned, f);
    u = (u + 0x7fff + ((u >> 16) & 1)) >> 16;
    return (short)u;
}
static __device__ inline float bf2f(short s) {
    unsigned u = ((unsigned)(unsigned short)s) << 16;
    return __builtin_bit_cast(float, u);
}

struct Params {
    const float *emb, *noise_init, *noise_final, *slots_mu, *slots_logsg,
                *mixing_co, *Wk, *bk, *Wq, *bq, *Wv, *bv, *ln_g, *ln_b;
    float *out;
    // workspace
    float *queries, *attn;
    float *s1p, *s2p;        // [BB*16][KK][DD] private partial moments
    float *off, *mix16, *colsum;
    float *ivtab;            // [KK][DD]  1/(sigma0^2+EPS), it=0 table
    short *Abf, *Kbf, *Vbf, *WtKV, *WqT, *slotbf, *F_bt;
};

// ===========================================================================
// 1) pre: u in [0,4992) : LN+cast | weight transpose | slot init + F/off init
//    Slot-init branch now ALSO: ivtab (b==0), zero F rows 8..15, off/mix/
//    colsum init (off = GLL_C0 - 0.5*sum_d log(|sg|+EPS), batch-independent
//    part; k_gemm's qmode blocks atomicAdd the -0.5*sum q^2*iv part).
// ===========================================================================
__global__ __launch_bounds__(256) void k_pre(Params p)
{
    __shared__ __align__(16) short eb[4352];
    int u = blockIdx.x, tid = threadIdx.x;
    if (u < 4096) {
        int row  = u * 4 + (tid >> 6);
        int lane = tid & 63;
        const float* e = p.emb + (size_t)row * DD + lane * 8;
        float4 v0 = *(const float4*)e;
        float4 v1 = *(const float4*)(e + 4);
        float v[8] = {v0.x, v0.y, v0.z, v0.w, v1.x, v1.y, v1.z, v1.w};
        float s = 0.0f;
#pragma unroll
        for (int j = 0; j < 8; j++) s += v[j];
#pragma unroll
        for (int off = 32; off; off >>= 1) s += __shfl_xor(s, off);
        float m = s * (1.0f / DD);
        float vs = 0.0f;
#pragma unroll
        for (int j = 0; j < 8; j++) { float d = v[j] - m; vs = fmaf(d, d, vs); }
#pragma unroll
        for (int off = 32; off; off >>= 1) vs += __shfl_xor(vs, off);
        float rstd = rsqrtf(vs * (1.0f / DD) + LN_EPS_);

        float4 g0 = *(const float4*)&p.ln_g[lane * 8];
        float4 g1 = *(const float4*)&p.ln_g[lane * 8 + 4];
        float4 b0 = *(const float4*)&p.ln_b[lane * 8];
        float4 b1 = *(const float4*)&p.ln_b[lane * 8 + 4];
        float g[8] = {g0.x, g0.y, g0.z, g0.w, g1.x, g1.y, g1.z, g1.w};
        float bb[8] = {b0.x, b0.y, b0.z, b0.w, b1.x, b1.y, b1.z, b1.w};
        short8 o;
#pragma unroll
        for (int j = 0; j < 8; j++) o[j] = f2bf(fmaf((v[j] - m) * rstd, g[j], bb[j]));
        *(short8*)&p.Abf[(size_t)row * DD + lane * 8] = o;
    } else if (u < 4864) {
        int idx = u - 4096;
        int z = idx >> 8, rem = idx & 255;
        const float* W = (z == 0) ? p.Wk : (z == 1) ? p.Wv : p.Wq;
        short* T; int nbase;
        if (z < 2) { T = p.WtKV; nbase = z * 512; } else { T = p.WqT; nbase = 0; }
        int k0 = (rem & 15) * 32, n0 = (rem >> 4) * 32;
        int tx = tid & 31, ty = tid >> 5;
        float (*t)[33] = (float (*)[33])eb;
#pragma unroll
        for (int q = 0; q < 4; q++)
            t[ty + q * 8][tx] = W[(size_t)(k0 + ty + q * 8) * DD + n0 + tx];
        __syncthreads();
#pragma unroll
        for (int q = 0; q < 4; q++)
            T[(size_t)(nbase + n0 + ty + q * 8) * DD + k0 + tx] = f2bf(t[tx][ty + q * 8]);
    } else {
        int idx = u - 4864;              // 0..127
        int b = idx >> 3, k = idx & 7;
        float* redf = (float*)eb;        // 256 floats, reuse LDS
        float ld = 0.0f;
#pragma unroll
        for (int q = 0; q < 2; q++) {
            int d = tid + q * 256;
            float sg = expf(p.slots_logsg[k * DD + d]);
            float sl = fmaf(sg, p.noise_init[((size_t)(b * KK + k)) * DD + d],
                            p.slots_mu[k * DD + d]);
            p.slotbf[((size_t)(b * KK + k)) * DD + d] = f2bf(sl);
            if (b == 0) p.ivtab[k * DD + d] = 1.0f / (sg * sg + EPS_);
            ld += logf(fabsf(sg) + EPS_);
        }
        // zero F row (b, k+8) once (never rewritten afterwards)
        {
            short4v zv = {0, 0, 0, 0};
            *(short4v*)&p.F_bt[(size_t)(b * 16 + 8 + k) * 1024 + tid * 4] = zv;
        }
        redf[tid] = ld;
        __syncthreads();
        for (int s = 128; s > 0; s >>= 1) {
            if (tid < s) redf[tid] += redf[tid + s];
            __syncthreads();
        }
        if (tid == 0) {
            p.off[b * 16 + k]       = GLL_C0 - 0.5f * redf[0];
            p.mix16[b * 16 + k]     = p.mixing_co[k];
            p.off[b * 16 + 8 + k]   = 0.0f;
            p.mix16[b * 16 + 8 + k] = 0.0f;
            p.colsum[b * KK + k]    = 0.0f;
        }
    }
}

// ===========================================================================
// 2) gemm: u in [0,1032) : 128x128 MFMA GEMM, global_load_lds staging
//    (round-2 verified).  qmode epilogue now ALSO writes F_bt rows (k<8)
//    and atomicAdds the -0.5*sum(q^2*iv) partial into off — absorbing
//    k_fprep0 (iv from ivtab, no expf here).
// ===========================================================================
__global__ __launch_bounds__(256) void k_gemm(Params p)
{
    __shared__ __align__(16) short smem[32768];   // 64 KB: As0|As1|Bs0|Bs1
    int u = blockIdx.x, tid = threadIdx.x;
    int w = tid >> 6, l = tid & 63;
    int x, by, qmode;
    if (u >= 1024) { qmode = 1; x = u - 1024; if (x >= 4) return; by = 128; }
    else           { qmode = 0; x = u >> 7;   by = u & 127; }
    const short* A  = qmode ? p.slotbf : p.Abf + (size_t)by * 128 * DD;
    const short* Bt = qmode ? p.WqT : p.WtKV;
    int row0 = qmode ? 0 : by * 128;
    int col0 = x * 128;

    int sr = l >> 3;
    int sg_off = ((l & 7) ^ sr) * 8;
    int mq = (w & 1) * 64, nq = (w >> 1) * 64;
    int fr = l & 15;
    int orow = (l >> 4) * 4, ocol = l & 15;

    auto STAGE = [&](int k0, int buf) {
        short* As_ = smem + buf * 8192;
        short* Bs_ = smem + 16384 + buf * 8192;
#pragma unroll
        for (int j = 0; j < 4; j++) {
            int rbj = w * 32 + j * 8;
            int r   = rbj + sr;
            __builtin_amdgcn_global_load_lds(
                (const __attribute__((address_space(1))) unsigned int*)
                    (A + (size_t)r * DD + k0 + sg_off),
                (__attribute__((address_space(3))) unsigned int*)
                    &As_[rbj * 64 + l * 8], 16, 0, 0);
            __builtin_amdgcn_global_load_lds(
                (const __attribute__((address_space(1))) unsigned int*)
                    (Bt + (size_t)(col0 + r) * DD + k0 + sg_off),
                (__attribute__((address_space(3))) unsigned int*)
                    &Bs_[rbj * 64 + l * 8], 16, 0, 0);
        }
    };

    f32x4 acc[4][4] = {};
    STAGE(0, 0);
    __syncthreads();
    for (int i = 0; i < 8; i++) {
        if (i < 7) STAGE((i + 1) * 64, (i + 1) & 1);   // in flight during compute
        const short* As_ = smem + (i & 1) * 8192;
        const short* Bs_ = smem + 16384 + (i & 1) * 8192;
#pragma unroll
        for (int kk = 0; kk < 2; kk++) {
            int g = kk * 4 + (l >> 4);
            short8 af[4], bfv[4];
#pragma unroll
            for (int mi = 0; mi < 4; mi++)
                af[mi] = *(const short8*)&As_[(mq + mi * 16 + fr) * 64 + (g ^ (fr & 7)) * 8];
#pragma unroll
            for (int ni = 0; ni < 4; ni++)
                bfv[ni] = *(const short8*)&Bs_[(nq + ni * 16 + fr) * 64 + (g ^ (fr & 7)) * 8];
#pragma unroll
            for (int mi = 0; mi < 4; mi++)
#pragma unroll
                for (int ni = 0; ni < 4; ni++)
                    acc[mi][ni] = __builtin_amdgcn_mfma_f32_16x16x32_bf16(
                        af[mi], bfv[ni], acc[mi][ni], 0, 0, 0);
        }
        __syncthreads();                  // ONE barrier per iteration (drains vmcnt)
    }

    float bvv[4];
#pragma unroll
    for (int ni = 0; ni < 4; ni++) {
        int col = col0 + nq + ni * 16 + ocol;
        bvv[ni] = qmode ? p.bq[col] : (x < 4 ? p.bk[col] : p.bv[col - 512]);
    }

    if (qmode) {
        float* cpart = (float*)smem;      // 128 floats (staging done)
        if (tid < 128) cpart[tid] = 0.0f;
        __syncthreads();
#pragma unroll
        for (int ni = 0; ni < 4; ni++) {
            int col = col0 + nq + ni * 16 + ocol;
#pragma unroll
            for (int mi = 0; mi < 4; mi++)
#pragma unroll
                for (int r = 0; r < 4; r++) {
                    int row = mq + mi * 16 + orow + r;     // = b*KK + k
                    float qv = acc[mi][ni][r] + bvv[ni];
                    p.queries[(size_t)row * DD + col] = qv;
                    float iv = p.ivtab[(row & 7) * DD + col];
                    int frow = (row >> 3) * 16 + (row & 7);
                    p.F_bt[(size_t)frow * 1024 + col]       = f2bf(-0.5f * iv);
                    p.F_bt[(size_t)frow * 1024 + 512 + col] = f2bf(qv * iv);
                    atomicAdd(&cpart[row], qv * qv * iv);
                }
        }
        __syncthreads();
        if (tid < 128)
            atomicAdd(&p.off[(tid >> 3) * 16 + (tid & 7)], -0.5f * cpart[tid]);
    } else {
        short* eb = smem;   // epilogue buffer (first 32 KB)
        short* dst = (x < 4) ? p.Kbf : p.Vbf;
        int ccol0 = (x & 3) * 128;
#pragma unroll
        for (int mi = 0; mi < 4; mi++)
#pragma unroll
            for (int r = 0; r < 4; r++) {
                int row = mq + mi * 16 + orow + r;
                int sw = ((row >> 2) & 3) << 1;
#pragma unroll
                for (int ni = 0; ni < 4; ni++) {
                    int colg = nq + ni * 16 + ocol;
                    eb[row * 128 + (((colg >> 3) ^ sw) * 8) + (colg & 7)] =
                        f2bf(acc[mi][ni][r] + bvv[ni]);
                }
            }
        __syncthreads();
#pragma unroll
        for (int i = 0; i < 8; i++) {
            int row = i * 16 + w * 4 + (l >> 4);
            int c = l & 15;
            int cc = c ^ (((row >> 2) & 3) << 1);
            short8 vv = *(const short8*)&eb[row * 128 + cc * 8];
            *(short8*)&dst[(size_t)(row0 + row) * 512 + ccol0 + c * 8] = vv;
        }
    }
}

// ===========================================================================
// 3) gllmu: u in [0,256), 512 threads, 64-row chunks (2 sub-tiles of the
//    round-4-verified 32-row phase-A pattern).  16 partial slots per batch
//    (was 32): fprep/final read traffic halved.  Phase B = verified
//    1 d-column/thread over 64 rows; private plain stores, NO atomics.
// ===========================================================================
__global__ __launch_bounds__(512) void k_gllmu(Params p, int itlast)
{
    __shared__ f32x4 red[3][2][64];    // 6 KB
    __shared__ float asml[64 * KK];    // 2 KB
    int u = blockIdx.x, tid = threadIdx.x;
    int w = tid >> 6, l = tid & 63;
    int b = u >> 4, chunk = u & 15;
    int n0 = chunk * 64;
    int t = w & 1, ks = w >> 1;        // row-tile, K-split (0..3)

    float csl = 0.0f;
#pragma unroll
    for (int st = 0; st < 2; st++) {
        const short* Ka = p.Kbf
            + ((size_t)(b * NN + n0 + st * 32 + t * 16 + (l & 15))) * 512
            + ks * 128 + (l >> 4) * 8;
        const short* Fi = p.F_bt + (size_t)(b * 16 + (l & 15)) * 1024
            + ks * 128 + (l >> 4) * 8;
        f32x4 acc0 = {}, acc1 = {};
#pragma unroll
        for (int j = 0; j < 4; j++) {
            short8 kf = *(const short8*)&Ka[j * 32];
            short8 f0 = *(const short8*)&Fi[j * 32];         // -0.5*invvar
            short8 f1 = *(const short8*)&Fi[j * 32 + 512];   // q*invvar
            short8 k2;
#pragma unroll
            for (int e = 0; e < 8; e++) {
                float kv = bf2f(kf[e]);
                k2[e] = f2bf(kv * kv);
            }
            acc0 = __builtin_amdgcn_mfma_f32_16x16x32_bf16(k2, f0, acc0, 0, 0, 0);
            acc1 = __builtin_amdgcn_mfma_f32_16x16x32_bf16(kf, f1, acc1, 0, 0, 0);
        }
        f32x4 acc = acc0 + acc1;

        if (ks) red[ks - 1][t][l] = acc;
        __syncthreads();
        if (ks == 0) {
#pragma unroll
            for (int i = 0; i < 3; i++) acc += red[i][t][l];
            int col = l & 15;
            int rloc = st * 32 + t * 16 + (l >> 4) * 4;
            float offv = p.off[b * 16 + col];
            float mixv = p.mix16[b * 16 + col];
            float a[4], den[4];
#pragma unroll
            for (int r = 0; r < 4; r++) { a[r] = mixv * (acc[r] + offv); den[r] = a[r]; }
#pragma unroll
            for (int mask = 1; mask <= 8; mask <<= 1)
#pragma unroll
                for (int r = 0; r < 4; r++) den[r] += __shfl_xor(den[r], mask);
            if (col < KK) {
#pragma unroll
                for (int r = 0; r < 4; r++) {
                    float vv = a[r] / den[r];
                    asml[(rloc + r) * KK + col] = vv;
                    if (itlast)
                        p.attn[((size_t)(b * NN + n0 + rloc + r)) * KK + col] = vv;
                    csl += vv;
                }
            }
        }
        __syncthreads();   // red/asml safe for next st; asml visible for B
    }
    if (ks == 0) {
        csl += __shfl_xor(csl, 16);
        csl += __shfl_xor(csl, 32);
        if (l < KK) atomicAdd(&p.colsum[b * KK + l], csl);
    }

    // ---- phase B: 1 d-column/thread over 64 rows; private partial slot ----
    float s1[KK] = {}, s2[KK] = {};
    const short* vb = p.Vbf + ((size_t)(b * NN + n0)) * DD + tid;
#pragma unroll 4
    for (int nn = 0; nn < 64; nn++) {
        float v = bf2f(vb[(size_t)nn * DD]);
        float vq = v * v;
        float4 a0 = *(const float4*)&asml[nn * KK];
        float4 a1 = *(const float4*)&asml[nn * KK + 4];
        float aa[8] = {a0.x, a0.y, a0.z, a0.w, a1.x, a1.y, a1.z, a1.w};
#pragma unroll
        for (int k = 0; k < KK; k++) {
            s1[k] = fmaf(aa[k], v, s1[k]);
            s2[k] = fmaf(aa[k], vq, s2[k]);
        }
    }
    size_t base = ((size_t)(b * 16 + chunk) * KK) * DD + tid;
#pragma unroll
    for (int k = 0; k < KK; k++) {
        p.s1p[base + (size_t)k * DD] = s1[k];
        p.s2p[base + (size_t)k * DD] = s2[k];
    }
}

// ===========================================================================
// 4) fprep: u in [0,128)  (verified; now 16 partial slots)
// ===========================================================================
__global__ __launch_bounds__(256) void k_fprep(Params p)
{
    __shared__ float red[512];
    int u = blockIdx.x, tid = threadIdx.x;
    int b = u >> 3, k = u & 7;
    float cs   = p.colsum[b * KK + k];
    float inv  = 1.0f / (cs + EPS_);
    float ssum = cs * inv;
    short* Fr = p.F_bt + (size_t)(b * 16 + k) * 1024;
    float* rc = red;
    float* rl = red + 256;
    float c = 0.0f, ld = 0.0f;
#pragma unroll
    for (int q = 0; q < 2; q++) {
        int d = tid * 2 + q;
        float s1 = 0.0f, s2 = 0.0f;
#pragma unroll
        for (int ns = 0; ns < 16; ns++) {
            size_t o = ((size_t)(b * 16 + ns) * KK + k) * DD + d;
            s1 += p.s1p[o];
            s2 += p.s2p[o];
        }
        float m  = s1 * inv;
        float sg = s2 * inv - m * m * (2.0f - ssum);
        float iv = 1.0f / (sg * sg + EPS_);
        float qv = p.queries[((size_t)(b * KK + k)) * DD + d];
        Fr[d]       = f2bf(-0.5f * iv);
        Fr[512 + d] = f2bf(qv * iv);
        c  = fmaf(qv * qv, iv, c);
        ld += logf(fabsf(sg) + EPS_);
    }
    rc[tid] = c; rl[tid] = ld;
    __syncthreads();
    for (int s = 128; s > 0; s >>= 1) {
        if (tid < s) { rc[tid] += rc[tid + s]; rl[tid] += rl[tid + s]; }
        __syncthreads();
    }
    if (tid == 0) {
        p.off[b * 16 + k]    = GLL_C0 - 0.5f * rl[0] - 0.5f * rc[0];
        p.mix16[b * 16 + k]  = ssum * (1.0f / NN);
        p.colsum[b * KK + k] = 0.0f;
    }
}

// ===========================================================================
// 5) final: u in [0,768)  (verified; now 16 partial slots)
// ===========================================================================
__global__ __launch_bounds__(256) void k_final(Params p)
{
    int u = blockIdx.x, tid = threadIdx.x;
    if (u < 256) {
        int gid = u * 256 + tid;
        int d = gid & 511;
        int k = (gid >> 9) & 7;
        int b = gid >> 12;
        float s1 = 0.0f, s2 = 0.0f;
#pragma unroll
        for (int ns = 0; ns < 16; ns++) {
            size_t o = ((size_t)(b * 16 + ns) * KK + k) * DD + d;
            s1 += p.s1p[o];
            s2 += p.s2p[o];
        }
        float cs   = p.colsum[b * KK + k];
        float inv  = 1.0f / (cs + EPS_);
        float ssum = cs * inv;
        float m    = s1 * inv;
        float sg   = s2 * inv - m * m * (2.0f - ssum);
        p.out[gid] = fmaf(fmaxf(fabsf(sg), EPS_), p.noise_final[gid], m);
    } else {
        int gid = (u - 256) * 256 + tid;
        int b = gid >> 13;
        int k = (gid >> 10) & 7;
        int n = gid & 1023;
        float cs = p.colsum[b * KK + k];
        p.out[BB * KK * DD + gid] =
            p.attn[((size_t)(b * NN + n)) * KK + k] / (cs + EPS_);
    }
}

// ===========================================================================
extern "C" void kernel_launch(void* const* d_in, const int* in_sizes, int n_in,
                              void* d_out, int out_size, void* d_ws, size_t ws_size,
                              hipStream_t stream)
{
    Params pp;
    pp.emb         = (const float*)d_in[0];
    pp.noise_init  = (const float*)d_in[1];
    pp.noise_final = (const float*)d_in[2];
    pp.slots_mu    = (const float*)d_in[3];
    pp.slots_logsg = (const float*)d_in[4];
    pp.mixing_co   = (const float*)d_in[5];
    pp.Wk          = (const float*)d_in[6];
    pp.bk          = (const float*)d_in[7];
    pp.Wq          = (const float*)d_in[8];
    pp.bq          = (const float*)d_in[9];
    pp.Wv          = (const float*)d_in[10];
    pp.bv          = (const float*)d_in[11];
    pp.ln_g        = (const float*)d_in[12];
    pp.ln_b        = (const float*)d_in[13];
    pp.out         = (float*)d_out;

    float* ws = (float*)d_ws;
    pp.queries = ws;                                   // 65536 f
    pp.attn    = pp.queries + BB * KK * DD;            // 131072 f
    pp.s1p     = pp.attn + BB * NN * KK;               // BB*16*KK*DD f
    pp.s2p     = pp.s1p + (size_t)BB * 16 * KK * DD;   // BB*16*KK*DD f
    pp.off     = pp.s2p + (size_t)BB * 16 * KK * DD;   // 256 f
    pp.mix16   = pp.off + BB * 16;                     // 256 f
    pp.colsum  = pp.mix16 + BB * 16;                   // 128 f
    pp.ivtab   = pp.colsum + BB * KK;                  // KK*DD f
    pp.Abf     = (short*)(pp.ivtab + KK * DD);
    pp.Kbf     = pp.Abf + (size_t)BB * NN * DD;
    pp.Vbf     = pp.Kbf + (size_t)BB * NN * DD;
    pp.WtKV    = pp.Vbf + (size_t)BB * NN * DD;
    pp.WqT     = pp.WtKV + (size_t)1024 * DD;
    pp.slotbf  = pp.WqT + (size_t)DD * DD;
    pp.F_bt    = pp.slotbf + (size_t)BB * KK * DD;

    k_pre<<<4992, 256, 0, stream>>>(pp);
    k_gemm<<<1032, 256, 0, stream>>>(pp);
    for (int it = 0; it < 3; it++) {
        k_gllmu<<<256, 512, 0, stream>>>(pp, it == 2);
        if (it < 2) k_fprep<<<128, 256, 0, stream>>>(pp);
    }
    k_final<<<768, 256, 0, stream>>>(pp);
}

// Round 6
// 201.435 us; speedup vs baseline: 1.6085x; 1.1047x over previous
//
#include <hip/hip_runtime.h>
#include <math.h>

// Problem constants
#define BB 16
#define NN 1024
#define DD 512
#define KK 8
#define EPS_ 1e-8f
#define LN_EPS_ 1e-5f
// -0.5 * D * log(2*pi)
#define GLL_C0 (-470.4965290007924f)

typedef __attribute__((ext_vector_type(8))) short short8;
typedef __attribute__((ext_vector_type(4))) short short4v;
typedef __attribute__((ext_vector_type(4))) float f32x4;
typedef __attribute__((ext_vector_type(4))) int int4v;

static __device__ inline short f2bf(float f) {
    unsigned u = __builtin_bit_cast(unsigned, f);
    u = (u + 0x7fff + ((u >> 16) & 1)) >> 16;
    return (short)u;
}
static __device__ inline float bf2f(short s) {
    unsigned u = ((unsigned)(unsigned short)s) << 16;
    return __builtin_bit_cast(float, u);
}

struct Params {
    const float *emb, *noise_init, *noise_final, *slots_mu, *slots_logsg,
                *mixing_co, *Wk, *bk, *Wq, *bq, *Wv, *bv, *ln_g, *ln_b;
    float *out;
    // workspace
    float *queries, *attn;
    float *s1p, *s2p;        // [BB*32][KK][DD] private partial moments
    float *off, *mix16, *colsum;
    float *ivtab;            // [KK][DD]  1/(sigma0^2+EPS), it=0 table
    short *Abf, *Kbf, *Vbf, *WtKV, *WqT, *slotbf, *F_bt;
};

// ===========================================================================
// 1) pre: u in [0,4992) : LN+cast | weight transpose | slot init + F/off init
//    (round-5 version, verified: ivtab, zero F rows 8..15, off/mix/colsum
//    init with the batch-independent off part)
// ===========================================================================
__global__ __launch_bounds__(256) void k_pre(Params p)
{
    __shared__ __align__(16) short eb[4352];
    int u = blockIdx.x, tid = threadIdx.x;
    if (u < 4096) {
        int row  = u * 4 + (tid >> 6);
        int lane = tid & 63;
        const float* e = p.emb + (size_t)row * DD + lane * 8;
        float4 v0 = *(const float4*)e;
        float4 v1 = *(const float4*)(e + 4);
        float v[8] = {v0.x, v0.y, v0.z, v0.w, v1.x, v1.y, v1.z, v1.w};
        float s = 0.0f;
#pragma unroll
        for (int j = 0; j < 8; j++) s += v[j];
#pragma unroll
        for (int off = 32; off; off >>= 1) s += __shfl_xor(s, off);
        float m = s * (1.0f / DD);
        float vs = 0.0f;
#pragma unroll
        for (int j = 0; j < 8; j++) { float d = v[j] - m; vs = fmaf(d, d, vs); }
#pragma unroll
        for (int off = 32; off; off >>= 1) vs += __shfl_xor(vs, off);
        float rstd = rsqrtf(vs * (1.0f / DD) + LN_EPS_);

        float4 g0 = *(const float4*)&p.ln_g[lane * 8];
        float4 g1 = *(const float4*)&p.ln_g[lane * 8 + 4];
        float4 b0 = *(const float4*)&p.ln_b[lane * 8];
        float4 b1 = *(const float4*)&p.ln_b[lane * 8 + 4];
        float g[8] = {g0.x, g0.y, g0.z, g0.w, g1.x, g1.y, g1.z, g1.w};
        float bb[8] = {b0.x, b0.y, b0.z, b0.w, b1.x, b1.y, b1.z, b1.w};
        short8 o;
#pragma unroll
        for (int j = 0; j < 8; j++) o[j] = f2bf(fmaf((v[j] - m) * rstd, g[j], bb[j]));
        *(short8*)&p.Abf[(size_t)row * DD + lane * 8] = o;
    } else if (u < 4864) {
        int idx = u - 4096;
        int z = idx >> 8, rem = idx & 255;
        const float* W = (z == 0) ? p.Wk : (z == 1) ? p.Wv : p.Wq;
        short* T; int nbase;
        if (z < 2) { T = p.WtKV; nbase = z * 512; } else { T = p.WqT; nbase = 0; }
        int k0 = (rem & 15) * 32, n0 = (rem >> 4) * 32;
        int tx = tid & 31, ty = tid >> 5;
        float (*t)[33] = (float (*)[33])eb;
#pragma unroll
        for (int q = 0; q < 4; q++)
            t[ty + q * 8][tx] = W[(size_t)(k0 + ty + q * 8) * DD + n0 + tx];
        __syncthreads();
#pragma unroll
        for (int q = 0; q < 4; q++)
            T[(size_t)(nbase + n0 + ty + q * 8) * DD + k0 + tx] = f2bf(t[tx][ty + q * 8]);
    } else {
        int idx = u - 4864;              // 0..127
        int b = idx >> 3, k = idx & 7;
        float* redf = (float*)eb;        // 256 floats, reuse LDS
        float ld = 0.0f;
#pragma unroll
        for (int q = 0; q < 2; q++) {
            int d = tid + q * 256;
            float sg = expf(p.slots_logsg[k * DD + d]);
            float sl = fmaf(sg, p.noise_init[((size_t)(b * KK + k)) * DD + d],
                            p.slots_mu[k * DD + d]);
            p.slotbf[((size_t)(b * KK + k)) * DD + d] = f2bf(sl);
            if (b == 0) p.ivtab[k * DD + d] = 1.0f / (sg * sg + EPS_);
            ld += logf(fabsf(sg) + EPS_);
        }
        // zero F row (b, k+8) once (never rewritten afterwards)
        {
            short4v zv = {0, 0, 0, 0};
            *(short4v*)&p.F_bt[(size_t)(b * 16 + 8 + k) * 1024 + tid * 4] = zv;
        }
        redf[tid] = ld;
        __syncthreads();
        for (int s = 128; s > 0; s >>= 1) {
            if (tid < s) redf[tid] += redf[tid + s];
            __syncthreads();
        }
        if (tid == 0) {
            p.off[b * 16 + k]       = GLL_C0 - 0.5f * redf[0];
            p.mix16[b * 16 + k]     = p.mixing_co[k];
            p.off[b * 16 + 8 + k]   = 0.0f;
            p.mix16[b * 16 + 8 + k] = 0.0f;
            p.colsum[b * KK + k]    = 0.0f;
        }
    }
}

// ===========================================================================
// 2) gemm: u in [0,1032) : 128x128 MFMA GEMM, global_load_lds staging
//    (round-2 verified).  qmode epilogue absorbs k_fprep0 (F_bt rows, off
//    q^2-part).  FIX this round: register ni-presum + 16-lane shfl tree
//    -> 256 LDS atomics/block (was 16K at 128-way contention, which
//    extended the kernel tail ~16 us).
// ===========================================================================
__global__ __launch_bounds__(256) void k_gemm(Params p)
{
    __shared__ __align__(16) short smem[32768];   // 64 KB: As0|As1|Bs0|Bs1
    int u = blockIdx.x, tid = threadIdx.x;
    int w = tid >> 6, l = tid & 63;
    int x, by, qmode;
    if (u >= 1024) { qmode = 1; x = u - 1024; if (x >= 4) return; by = 128; }
    else           { qmode = 0; x = u >> 7;   by = u & 127; }
    const short* A  = qmode ? p.slotbf : p.Abf + (size_t)by * 128 * DD;
    const short* Bt = qmode ? p.WqT : p.WtKV;
    int row0 = qmode ? 0 : by * 128;
    int col0 = x * 128;

    int sr = l >> 3;
    int sg_off = ((l & 7) ^ sr) * 8;
    int mq = (w & 1) * 64, nq = (w >> 1) * 64;
    int fr = l & 15;
    int orow = (l >> 4) * 4, ocol = l & 15;

    auto STAGE = [&](int k0, int buf) {
        short* As_ = smem + buf * 8192;
        short* Bs_ = smem + 16384 + buf * 8192;
#pragma unroll
        for (int j = 0; j < 4; j++) {
            int rbj = w * 32 + j * 8;
            int r   = rbj + sr;
            __builtin_amdgcn_global_load_lds(
                (const __attribute__((address_space(1))) unsigned int*)
                    (A + (size_t)r * DD + k0 + sg_off),
                (__attribute__((address_space(3))) unsigned int*)
                    &As_[rbj * 64 + l * 8], 16, 0, 0);
            __builtin_amdgcn_global_load_lds(
                (const __attribute__((address_space(1))) unsigned int*)
                    (Bt + (size_t)(col0 + r) * DD + k0 + sg_off),
                (__attribute__((address_space(3))) unsigned int*)
                    &Bs_[rbj * 64 + l * 8], 16, 0, 0);
        }
    };

    f32x4 acc[4][4] = {};
    STAGE(0, 0);
    __syncthreads();
    for (int i = 0; i < 8; i++) {
        if (i < 7) STAGE((i + 1) * 64, (i + 1) & 1);   // in flight during compute
        const short* As_ = smem + (i & 1) * 8192;
        const short* Bs_ = smem + 16384 + (i & 1) * 8192;
#pragma unroll
        for (int kk = 0; kk < 2; kk++) {
            int g = kk * 4 + (l >> 4);
            short8 af[4], bfv[4];
#pragma unroll
            for (int mi = 0; mi < 4; mi++)
                af[mi] = *(const short8*)&As_[(mq + mi * 16 + fr) * 64 + (g ^ (fr & 7)) * 8];
#pragma unroll
            for (int ni = 0; ni < 4; ni++)
                bfv[ni] = *(const short8*)&Bs_[(nq + ni * 16 + fr) * 64 + (g ^ (fr & 7)) * 8];
#pragma unroll
            for (int mi = 0; mi < 4; mi++)
#pragma unroll
                for (int ni = 0; ni < 4; ni++)
                    acc[mi][ni] = __builtin_amdgcn_mfma_f32_16x16x32_bf16(
                        af[mi], bfv[ni], acc[mi][ni], 0, 0, 0);
        }
        __syncthreads();                  // ONE barrier per iteration (drains vmcnt)
    }

    float bvv[4];
#pragma unroll
    for (int ni = 0; ni < 4; ni++) {
        int col = col0 + nq + ni * 16 + ocol;
        bvv[ni] = qmode ? p.bq[col] : (x < 4 ? p.bk[col] : p.bv[col - 512]);
    }

    if (qmode) {
        float* cpart = (float*)smem;      // 128 floats (staging done)
        if (tid < 128) cpart[tid] = 0.0f;
        __syncthreads();
        float csum[4][4];                 // per (mi,r), summed over ni cols
#pragma unroll
        for (int mi = 0; mi < 4; mi++)
#pragma unroll
            for (int r = 0; r < 4; r++) csum[mi][r] = 0.0f;
#pragma unroll
        for (int ni = 0; ni < 4; ni++) {
            int col = col0 + nq + ni * 16 + ocol;
#pragma unroll
            for (int mi = 0; mi < 4; mi++)
#pragma unroll
                for (int r = 0; r < 4; r++) {
                    int row = mq + mi * 16 + orow + r;     // = b*KK + k
                    float qv = acc[mi][ni][r] + bvv[ni];
                    p.queries[(size_t)row * DD + col] = qv;
                    float iv = p.ivtab[(row & 7) * DD + col];
                    int frow = (row >> 3) * 16 + (row & 7);
                    p.F_bt[(size_t)frow * 1024 + col]       = f2bf(-0.5f * iv);
                    p.F_bt[(size_t)frow * 1024 + 512 + col] = f2bf(qv * iv);
                    csum[mi][r] = fmaf(qv * qv, iv, csum[mi][r]);
                }
        }
        // reduce over the 16-lane col group; lane (l&15)==0 holds the sum
#pragma unroll
        for (int mask = 1; mask <= 8; mask <<= 1)
#pragma unroll
            for (int mi = 0; mi < 4; mi++)
#pragma unroll
                for (int r = 0; r < 4; r++)
                    csum[mi][r] += __shfl_xor(csum[mi][r], mask);
        if ((l & 15) == 0) {
#pragma unroll
            for (int mi = 0; mi < 4; mi++)
#pragma unroll
                for (int r = 0; r < 4; r++) {
                    int row = mq + mi * 16 + orow + r;
                    atomicAdd(&cpart[row], csum[mi][r]);
                }
        }
        __syncthreads();
        if (tid < 128)
            atomicAdd(&p.off[(tid >> 3) * 16 + (tid & 7)], -0.5f * cpart[tid]);
    } else {
        short* eb = smem;   // epilogue buffer (first 32 KB)
        short* dst = (x < 4) ? p.Kbf : p.Vbf;
        int ccol0 = (x & 3) * 128;
#pragma unroll
        for (int mi = 0; mi < 4; mi++)
#pragma unroll
            for (int r = 0; r < 4; r++) {
                int row = mq + mi * 16 + orow + r;
                int sw = ((row >> 2) & 3) << 1;
#pragma unroll
                for (int ni = 0; ni < 4; ni++) {
                    int colg = nq + ni * 16 + ocol;
                    eb[row * 128 + (((colg >> 3) ^ sw) * 8) + (colg & 7)] =
                        f2bf(acc[mi][ni][r] + bvv[ni]);
                }
            }
        __syncthreads();
#pragma unroll
        for (int i = 0; i < 8; i++) {
            int row = i * 16 + w * 4 + (l >> 4);
            int c = l & 15;
            int cc = c ^ (((row >> 2) & 3) << 1);
            short8 vv = *(const short8*)&eb[row * 128 + cc * 8];
            *(short8*)&dst[(size_t)(row0 + row) * 512 + ccol0 + c * 8] = vv;
        }
    }
}

// ===========================================================================
// 3) gllmu: u in [0,512), 512 threads, 32-row chunks (round-2 verified:
//    8 waves = 2 row-tiles x 4 K-splits, LDS reduce, normalize, colsum
//    atomics, phase B 1 d/thread, private partial stores, attn write only
//    on last iteration).
// ===========================================================================
__global__ __launch_bounds__(512) void k_gllmu(Params p, int itlast)
{
    __shared__ f32x4 red[3][2][64];   // 6 KB
    __shared__ float asml[32 * KK];   // 1 KB
    int u = blockIdx.x, tid = threadIdx.x;
    int w = tid >> 6, l = tid & 63;
    int b = u >> 5, chunk = u & 31;
    int n0 = chunk * 32;
    int t = w & 1, ks = w >> 1;       // row-tile, K-split (0..3)

    // ---- phase A ----
    const short* Ka = p.Kbf + ((size_t)(b * NN + n0 + t * 16 + (l & 15))) * 512
                      + ks * 128 + (l >> 4) * 8;
    const short* Fi = p.F_bt + (size_t)(b * 16 + (l & 15)) * 1024
                      + ks * 128 + (l >> 4) * 8;
    f32x4 acc0 = {}, acc1 = {};
#pragma unroll
    for (int j = 0; j < 4; j++) {
        short8 kf = *(const short8*)&Ka[j * 32];
        short8 f0 = *(const short8*)&Fi[j * 32];         // -0.5*invvar
        short8 f1 = *(const short8*)&Fi[j * 32 + 512];   // q*invvar
        short8 k2;
#pragma unroll
        for (int e = 0; e < 8; e++) {
            float kv = bf2f(kf[e]);
            k2[e] = f2bf(kv * kv);
        }
        acc0 = __builtin_amdgcn_mfma_f32_16x16x32_bf16(k2, f0, acc0, 0, 0, 0);
        acc1 = __builtin_amdgcn_mfma_f32_16x16x32_bf16(kf, f1, acc1, 0, 0, 0);
    }
    f32x4 acc = acc0 + acc1;

    if (ks) red[ks - 1][t][l] = acc;
    __syncthreads();
    if (ks == 0) {
#pragma unroll
        for (int i = 0; i < 3; i++) acc += red[i][t][l];
        int col = l & 15;
        int rloc = t * 16 + (l >> 4) * 4;
        float offv = p.off[b * 16 + col];
        float mixv = p.mix16[b * 16 + col];
        float a[4], den[4];
#pragma unroll
        for (int r = 0; r < 4; r++) {
            a[r] = mixv * (acc[r] + offv);
            den[r] = a[r];
        }
#pragma unroll
        for (int mask = 1; mask <= 8; mask <<= 1)
#pragma unroll
            for (int r = 0; r < 4; r++) den[r] += __shfl_xor(den[r], mask);
        float csl = 0.0f;
        if (col < KK) {
#pragma unroll
            for (int r = 0; r < 4; r++) {
                float vv = a[r] / den[r];
                asml[(rloc + r) * KK + col] = vv;
                if (itlast)
                    p.attn[((size_t)(b * NN + n0 + rloc + r)) * KK + col] = vv;
                csl += vv;
            }
        }
        csl += __shfl_xor(csl, 16);
        csl += __shfl_xor(csl, 32);
        if (l < KK) atomicAdd(&p.colsum[b * KK + l], csl);
    }
    __syncthreads();

    // ---- phase B: 512 threads, one d-column each over 32 rows ----
    float s1[KK] = {}, s2[KK] = {};
    const short* vb = p.Vbf + ((size_t)(b * NN + n0)) * DD + tid;
#pragma unroll 4
    for (int nn = 0; nn < 32; nn++) {
        float v = bf2f(vb[(size_t)nn * DD]);
        float vq = v * v;
        float4 a0 = *(const float4*)&asml[nn * KK];
        float4 a1 = *(const float4*)&asml[nn * KK + 4];
        float aa[8] = {a0.x, a0.y, a0.z, a0.w, a1.x, a1.y, a1.z, a1.w};
#pragma unroll
        for (int k = 0; k < KK; k++) {
            s1[k] = fmaf(aa[k], v, s1[k]);
            s2[k] = fmaf(aa[k], vq, s2[k]);
        }
    }
    size_t base = ((size_t)(b * 32 + chunk) * KK) * DD + tid;
#pragma unroll
    for (int k = 0; k < KK; k++) {
        p.s1p[base + (size_t)k * DD] = s1[k];
        p.s2p[base + (size_t)k * DD] = s2[k];
    }
}

// ===========================================================================
// 4) fprep: u in [0,128)  (round-2 verified, 32 partial slots)
// ===========================================================================
__global__ __launch_bounds__(256) void k_fprep(Params p)
{
    __shared__ float red[512];
    int u = blockIdx.x, tid = threadIdx.x;
    int b = u >> 3, k = u & 7;
    float cs   = p.colsum[b * KK + k];
    float inv  = 1.0f / (cs + EPS_);
    float ssum = cs * inv;
    short* Fr = p.F_bt + (size_t)(b * 16 + k) * 1024;
    float* rc = red;
    float* rl = red + 256;
    float c = 0.0f, ld = 0.0f;
#pragma unroll
    for (int q = 0; q < 2; q++) {
        int d = tid * 2 + q;
        float s1 = 0.0f, s2 = 0.0f;
#pragma unroll
        for (int ns = 0; ns < 32; ns++) {
            size_t o = ((size_t)(b * 32 + ns) * KK + k) * DD + d;
            s1 += p.s1p[o];
            s2 += p.s2p[o];
        }
        float m  = s1 * inv;
        float sg = s2 * inv - m * m * (2.0f - ssum);
        float iv = 1.0f / (sg * sg + EPS_);
        float qv = p.queries[((size_t)(b * KK + k)) * DD + d];
        Fr[d]       = f2bf(-0.5f * iv);
        Fr[512 + d] = f2bf(qv * iv);
        c  = fmaf(qv * qv, iv, c);
        ld += logf(fabsf(sg) + EPS_);
    }
    rc[tid] = c; rl[tid] = ld;
    __syncthreads();
    for (int s = 128; s > 0; s >>= 1) {
        if (tid < s) { rc[tid] += rc[tid + s]; rl[tid] += rl[tid + s]; }
        __syncthreads();
    }
    if (tid == 0) {
        p.off[b * 16 + k]    = GLL_C0 - 0.5f * rl[0] - 0.5f * rc[0];
        p.mix16[b * 16 + k]  = ssum * (1.0f / NN);
        p.colsum[b * KK + k] = 0.0f;
    }
}

// ===========================================================================
// 5) final: u in [0,768)  (round-2 verified, 32 partial slots)
// ===========================================================================
__global__ __launch_bounds__(256) void k_final(Params p)
{
    int u = blockIdx.x, tid = threadIdx.x;
    if (u < 256) {
        int gid = u * 256 + tid;
        int d = gid & 511;
        int k = (gid >> 9) & 7;
        int b = gid >> 12;
        float s1 = 0.0f, s2 = 0.0f;
#pragma unroll
        for (int ns = 0; ns < 32; ns++) {
            size_t o = ((size_t)(b * 32 + ns) * KK + k) * DD + d;
            s1 += p.s1p[o];
            s2 += p.s2p[o];
        }
        float cs   = p.colsum[b * KK + k];
        float inv  = 1.0f / (cs + EPS_);
        float ssum = cs * inv;
        float m    = s1 * inv;
        float sg   = s2 * inv - m * m * (2.0f - ssum);
        p.out[gid] = fmaf(fmaxf(fabsf(sg), EPS_), p.noise_final[gid], m);
    } else {
        int gid = (u - 256) * 256 + tid;
        int b = gid >> 13;
        int k = (gid >> 10) & 7;
        int n = gid & 1023;
        float cs = p.colsum[b * KK + k];
        p.out[BB * KK * DD + gid] =
            p.attn[((size_t)(b * NN + n)) * KK + k] / (cs + EPS_);
    }
}

// ===========================================================================
extern "C" void kernel_launch(void* const* d_in, const int* in_sizes, int n_in,
                              void* d_out, int out_size, void* d_ws, size_t ws_size,
                              hipStream_t stream)
{
    Params pp;
    pp.emb         = (const float*)d_in[0];
    pp.noise_init  = (const float*)d_in[1];
    pp.noise_final = (const float*)d_in[2];
    pp.slots_mu    = (const float*)d_in[3];
    pp.slots_logsg = (const float*)d_in[4];
    pp.mixing_co   = (const float*)d_in[5];
    pp.Wk          = (const float*)d_in[6];
    pp.bk          = (const float*)d_in[7];
    pp.Wq          = (const float*)d_in[8];
    pp.bq          = (const float*)d_in[9];
    pp.Wv          = (const float*)d_in[10];
    pp.bv          = (const float*)d_in[11];
    pp.ln_g        = (const float*)d_in[12];
    pp.ln_b        = (const float*)d_in[13];
    pp.out         = (float*)d_out;

    float* ws = (float*)d_ws;
    pp.queries = ws;                                   // 65536 f
    pp.attn    = pp.queries + BB * KK * DD;            // 131072 f
    pp.s1p     = pp.attn + BB * NN * KK;               // BB*32*KK*DD f
    pp.s2p     = pp.s1p + (size_t)BB * 32 * KK * DD;   // BB*32*KK*DD f
    pp.off     = pp.s2p + (size_t)BB * 32 * KK * DD;   // 256 f
    pp.mix16   = pp.off + BB * 16;                     // 256 f
    pp.colsum  = pp.mix16 + BB * 16;                   // 128 f
    pp.ivtab   = pp.colsum + BB * KK;                  // KK*DD f
    pp.Abf     = (short*)(pp.ivtab + KK * DD);
    pp.Kbf     = pp.Abf + (size_t)BB * NN * DD;
    pp.Vbf     = pp.Kbf + (size_t)BB * NN * DD;
    pp.WtKV    = pp.Vbf + (size_t)BB * NN * DD;
    pp.WqT     = pp.WtKV + (size_t)1024 * DD;
    pp.slotbf  = pp.WqT + (size_t)DD * DD;
    pp.F_bt    = pp.slotbf + (size_t)BB * KK * DD;

    k_pre<<<4992, 256, 0, stream>>>(pp);
    k_gemm<<<1032, 256, 0, stream>>>(pp);
    for (int it = 0; it < 3; it++) {
        k_gllmu<<<512, 512, 0, stream>>>(pp, it == 2);
        if (it < 2) k_fprep<<<128, 256, 0, stream>>>(pp);
    }
    k_final<<<768, 256, 0, stream>>>(pp);
}